// Round 9
// baseline (422.793 us; speedup 1.0000x reference)
//
#include <hip/hip_runtime.h>
#include <math.h>

#define N_NODES 50000
#define MPAD    50048                              // 64 * 782 = 32 * 1564, padded row count
#define N_EDGES 800000
#define FDIM    128
#define NGRAPH  128

// deterministic multi-split CSR build
#define NCB   196                                  // coarse buckets (dst>>8, 256 nodes each)
#define CBN   256                                  // nodes per coarse bucket
#define ABLK  256                                  // histogram/scatter blocks
#define EPB   (N_EDGES / ABLK)                     // 3125 edges per block (exact)
#define CVT_BLOCKS ((MPAD * FDIM / 4 + 255) / 256) // 6256 convert blocks
#define WCONV_BLOCKS 640                           // convert_w work folded into pre

// R16: per-node edges (src-chunk)-sorted (kept). R19: 32-node tiles (kept).
// R20: two-kernel scan RESTORED (R22's merged single-block scan cost ~7us).
// R23: fp4-e2m1 gather rows (64 B = ONE request/edge, hot array 3.2 MB <= 4 MB
// per-XCD L2). Tests latency-residency at CONSTANT request count (R21 doubled
// requests -> confounded). LDS byte-pair LUT decode; nontemporal streams
// (self-term h, out stores) protect L2 residency of the fp4 array.
#define NCHUNK 8
#define CHUNK_OF(s) ((int)(((u32)(s) * 671u) >> 22))   // monotone, ~6251 nodes/chunk, 0..7

typedef __attribute__((ext_vector_type(8))) short short8;   // 8 bf16 = 4 VGPRs
typedef __attribute__((ext_vector_type(4))) float f32x4;
typedef unsigned int u32;

__device__ __forceinline__ unsigned short f2bf(float f) {   // RNE
    unsigned int u = __float_as_uint(f);
    return (unsigned short)((u + 0x7FFFu + ((u >> 16) & 1u)) >> 16);
}
__device__ __forceinline__ float bflo(unsigned int u) { return __uint_as_float(u << 16); }

// ---- fp4 e2m1 helpers ----
// encode: nearest value in {0,.5,1,1.5,2,3,4,6} (midpoint thresholds), sign bit3
__device__ __forceinline__ u32 f2fp4(float f) {
    float a = fabsf(f);
    u32 c = (u32)(a >= 0.25f) + (u32)(a >= 0.75f) + (u32)(a >= 1.25f) + (u32)(a >= 1.75f)
          + (u32)(a >= 2.5f)  + (u32)(a >= 3.5f)  + (u32)(a >= 5.0f);
    return c | (f < 0.f ? 8u : 0u);
}
// decode nibble -> top 16 bits of the f32 value
__device__ __forceinline__ u32 fp4top16(u32 nib) {
    u32 tt = nib & 7u, m = tt & 1u, e = tt >> 1;
    u32 h = e ? (((126u + e) << 7) | (m << 6)) : (m * 0x3F00u);
    return h | ((nib & 8u) << 12);
}

// decode one u32 (8 fp4) via LDS byte-pair LUT -> acc[off..off+7]
#define DEC8(ww, off) { \
    u32 l0 = lut[(ww) & 0xFFu]; \
    u32 l1 = lut[((ww) >> 8) & 0xFFu]; \
    u32 l2 = lut[((ww) >> 16) & 0xFFu]; \
    u32 l3 = lut[(ww) >> 24]; \
    acc[(off)+0] += __uint_as_float(l0 << 16); acc[(off)+1] += __uint_as_float(l0 & 0xFFFF0000u); \
    acc[(off)+2] += __uint_as_float(l1 << 16); acc[(off)+3] += __uint_as_float(l1 & 0xFFFF0000u); \
    acc[(off)+4] += __uint_as_float(l2 << 16); acc[(off)+5] += __uint_as_float(l2 & 0xFFFF0000u); \
    acc[(off)+6] += __uint_as_float(l3 << 16); acc[(off)+7] += __uint_as_float(l3 & 0xFFFF0000u); }

struct WPtrs { const float* wl[5]; const float* wr[5]; };

// ------- pre: x convert | edge histogram | weight convert (fused, routed by blockIdx) -----
__global__ __launch_bounds__(256) void pre_kernel(const float* __restrict__ x,
                                                  unsigned short* __restrict__ xb,
                                                  unsigned char* __restrict__ xb4,
                                                  const int* __restrict__ edges,
                                                  int* __restrict__ g_hist,
                                                  WPtrs wp,
                                                  unsigned short* __restrict__ wcat,
                                                  const int* __restrict__ batch,
                                                  float* __restrict__ gsum,
                                                  float* __restrict__ invcnt) {
    __shared__ int hist[NCB];
    int t = threadIdx.x;
    if (blockIdx.x < CVT_BLOCKS) {
        int i = blockIdx.x * 256 + t;
        if (i >= MPAD * FDIM / 4) return;
        int base = i * 4;
        uint2 o;
        unsigned short p4 = 0;
        if (base < N_NODES * FDIM) {
            float4 v = *(const float4*)&x[base];
            o.x = (u32)f2bf(v.x) | ((u32)f2bf(v.y) << 16);
            o.y = (u32)f2bf(v.z) | ((u32)f2bf(v.w) << 16);
            p4 = (unsigned short)(f2fp4(v.x) | (f2fp4(v.y) << 4) |
                                  (f2fp4(v.z) << 8) | (f2fp4(v.w) << 12));
        } else { o.x = 0u; o.y = 0u; }
        *(uint2*)&xb[base] = o;
        *(unsigned short*)&xb4[base >> 1] = p4;
    } else if (blockIdx.x < CVT_BLOCKS + ABLK) {
        int blk = blockIdx.x - CVT_BLOCKS;
        if (t < NCB) hist[t] = 0;
        __syncthreads();
        int beg = blk * EPB, end = beg + EPB;
        for (int i = beg + t; i < end; i += 256) {
            int2 ed = ((const int2*)edges)[i];
            atomicAdd(&hist[ed.y >> 8], 1);
        }
        __syncthreads();
        if (t < NCB) g_hist[t * ABLK + blk] = hist[t];
    } else {
        int tg = (blockIdx.x - CVT_BLOCKS - ABLK) * 256 + t;   // 0 .. 163839
        if (tg < NGRAPH * FDIM) gsum[tg] = 0.0f;
        if (tg < NGRAPH) {
            int g = tg;
            int lo = 0, hi = N_NODES;
            while (lo < hi) { int mid = (lo + hi) >> 1; if (batch[mid] < g) lo = mid + 1; else hi = mid; }
            int beg = lo;
            hi = N_NODES;
            while (lo < hi) { int mid = (lo + hi) >> 1; if (batch[mid] < g + 1) lo = mid + 1; else hi = mid; }
            invcnt[g] = 1.0f / (float)max(lo - beg, 1);
        }
        int l = tg >> 15;
        int rem = tg & 32767;
        int k = rem >> 7;        // 0..255
        int n = rem & 127;       // coalesced read over n
        const float* W = (k < 128) ? wp.wl[l] : wp.wr[l];
        float v = W[(k & 127) * 128 + n];
        wcat[((size_t)l << 15) + n * 256 + k] = f2bf(v);
    }
}

// ---------------- scan1: per-bucket wave-parallel exclusive scan over 256 blocks ----------
__global__ __launch_bounds__(64) void scan1_kernel(const int* __restrict__ g_hist,
                                                   int* __restrict__ g_base,
                                                   int* __restrict__ cbtotal) {
    int cbi = blockIdx.x, l = threadIdx.x;          // 196 blocks x 1 wave
    int4 v = ((const int4*)(g_hist + cbi * ABLK))[l];
    int s1 = v.x + v.y, s2 = s1 + v.z, s3 = s2 + v.w;   // lane-local inclusive
    int inc = s3;
    #pragma unroll
    for (int off = 1; off < 64; off <<= 1) {
        int nv = __shfl_up(inc, off, 64);
        if (l >= off) inc += nv;
    }
    int excl = inc - s3;
    int4 o; o.x = excl; o.y = excl + v.x; o.z = excl + s1; o.w = excl + s2;
    ((int4*)(g_base + cbi * ABLK))[l] = o;
    if (l == 63) cbtotal[cbi] = inc;
}

// ---------------- scan2: tiny exclusive scan of 196 bucket totals -> cbbase ----------
__global__ __launch_bounds__(256) void scan2_kernel(const int* __restrict__ cbtotal,
                                                    int* __restrict__ cbbase,
                                                    int* __restrict__ row_ptr) {
    __shared__ int s[NCB];
    int t = threadIdx.x;
    if (t < NCB) s[t] = cbtotal[t];
    __syncthreads();
    if (t == 0) {
        int run = 0;
        for (int i = 0; i < NCB; ++i) { int v = s[i]; s[i] = run; run += v; }
        row_ptr[N_NODES] = N_EDGES;
    }
    __syncthreads();
    if (t < NCB) cbbase[t] = s[t];
}

// ---------------- A2: deterministic scatter into coarse buckets ----------------
__global__ __launch_bounds__(256) void scatter_kernel(const int* __restrict__ edges,
                                                      const int* __restrict__ g_base,
                                                      const int* __restrict__ cbbase,
                                                      u32* __restrict__ coarse) {
    __shared__ int cur[NCB];
    int t = threadIdx.x, blk = blockIdx.x;
    if (t < NCB) cur[t] = g_base[t * ABLK + blk] + cbbase[t];
    __syncthreads();
    int beg = blk * EPB, end = beg + EPB;
    for (int i = beg + t; i < end; i += 256) {
        int2 ed = ((const int2*)edges)[i];   // x=src, y=dst
        int cb = ed.y >> 8;
        int pos = atomicAdd(&cur[cb], 1);
        coarse[pos] = ((u32)(ed.y & 255) << 16) | (u32)ed.x;
    }
}

// ---------------- B: per-coarse-bucket LDS counting sort by (dst, src-chunk) ----------
__global__ __launch_bounds__(256) void csr_kernel(const int* __restrict__ cbbase,
                                                  const int* __restrict__ cbtotal,
                                                  const u32* __restrict__ coarse,
                                                  int* __restrict__ csr_src,
                                                  int* __restrict__ row_ptr,
                                                  float* __restrict__ invdeg) {
    __shared__ int cnt[CBN][NCHUNK];   // 8 KB: per-(dst,chunk) cell counts -> cursors
    __shared__ int dbase[CBN];         // per-dst totals -> absolute dst bases
    int cb = blockIdx.x, t = threadIdx.x;
    int n = cbtotal[cb], base = cbbase[cb];
    #pragma unroll
    for (int c0 = 0; c0 < NCHUNK; ++c0) cnt[t][c0] = 0;
    __syncthreads();
    const u32* ce = coarse + base;
    for (int i = t; i < n; i += 256) {
        u32 ev = ce[i];
        atomicAdd(&cnt[ev >> 16][CHUNK_OF(ev & 0xFFFFu)], 1);
    }
    __syncthreads();
    {   // per-dst exclusive scan over its 8 chunk cells (thread t owns dst t)
        int run = 0;
        #pragma unroll
        for (int c0 = 0; c0 < NCHUNK; ++c0) { int v = cnt[t][c0]; cnt[t][c0] = run; run += v; }
        dbase[t] = run;
    }
    __syncthreads();
    if (t == 0) {   // exclusive scan over 256 dst totals (parallel across 196 blocks)
        int run = base;
        for (int d = 0; d < CBN; ++d) { int v = dbase[d]; dbase[d] = run; run += v; }
    }
    __syncthreads();
    {   // absolute cell starts; emit row_ptr + invdeg before cursors move
        int db = dbase[t];
        int deg = ((t == CBN - 1) ? base + n : dbase[t + 1]) - db;
        #pragma unroll
        for (int c0 = 0; c0 < NCHUNK; ++c0) cnt[t][c0] += db;
        int node = cb * CBN + t;
        if (node < N_NODES) {
            row_ptr[node] = db;
            invdeg[node] = 1.0f / (float)max(deg, 1);
        }
    }
    __syncthreads();
    for (int i = t; i < n; i += 256) {
        u32 ev = ce[i];
        int pos = atomicAdd(&cnt[ev >> 16][CHUNK_OF(ev & 0xFFFFu)], 1);
        csr_src[pos] = (int)(ev & 0xFFFFu);
    }
}

// ---------------- fused SAGE layer: fp4 gather agg tile into LDS, then MFMA ----------------
// R23: 32-node tiles, 256 thr. Gather: 32 slots x 8 lanes, uint2 fp4 rows
// (64 B = ONE request/edge). LDS byte-pair LUT decode; f32 accumulate.
// Self-term h (bf16) reads + out stores are NONTEMPORAL to keep h4 L2-resident.
__global__ __launch_bounds__(256) void sage_fused_kernel(
        const unsigned short* __restrict__ h,    // [MPAD][128] bf16 (self term)
        const unsigned char*  __restrict__ h4,   // [MPAD][64 B] fp4 (gather)
        const int* __restrict__ row_ptr,
        const int* __restrict__ csr_src,
        const float* __restrict__ invdeg,
        const unsigned short* __restrict__ Wcat, // [128 n][256 k] bf16
        const float* __restrict__ bias,
        unsigned short* __restrict__ out,
        unsigned char*  __restrict__ out4,       // fp4 copy for next layer's gather (null l=4)
        const int* __restrict__ pool_batch,      // null for layers 1-4
        float* __restrict__ gsum) {
    __shared__ unsigned short As[32][136];
    __shared__ u32 lut[256];                     // byte -> two packed f32-top16s
    int t = threadIdx.x;
    int node0 = blockIdx.x * 32;

    {   // LUT init (one entry per thread)
        u32 b = (u32)t;
        lut[t] = fp4top16(b & 0xFu) | (fp4top16(b >> 4) << 16);
    }
    __syncthreads();

    // ---- phase 1: gather (32 node-slots x 8 lanes, one pass) ----
    {
        int slot = t >> 3;       // 0..31
        int lane = t & 7;
        int c = lane * 16;       // feature offset (16 fp4 per lane)
        int node = node0 + slot;
        float acc[16];
        #pragma unroll
        for (int i = 0; i < 16; ++i) acc[i] = 0.f;
        if (node < N_NODES) {
            int beg = row_ptr[node], end = row_ptr[node + 1];
            int e = beg;
            for (; e + 4 <= end; e += 4) {
                int s0 = csr_src[e + 0];
                int s1 = csr_src[e + 1];
                int s2 = csr_src[e + 2];
                int s3 = csr_src[e + 3];
                uint2 w0 = *(const uint2*)&h4[(size_t)s0 * 64 + lane * 8];
                uint2 w1 = *(const uint2*)&h4[(size_t)s1 * 64 + lane * 8];
                uint2 w2 = *(const uint2*)&h4[(size_t)s2 * 64 + lane * 8];
                uint2 w3 = *(const uint2*)&h4[(size_t)s3 * 64 + lane * 8];
                DEC8(w0.x, 0); DEC8(w0.y, 8);
                DEC8(w1.x, 0); DEC8(w1.y, 8);
                DEC8(w2.x, 0); DEC8(w2.y, 8);
                DEC8(w3.x, 0); DEC8(w3.y, 8);
            }
            for (; e < end; ++e) {
                int s = csr_src[e];
                uint2 w = *(const uint2*)&h4[(size_t)s * 64 + lane * 8];
                DEC8(w.x, 0); DEC8(w.y, 8);
            }
            float inv = invdeg[node];
            #pragma unroll
            for (int i = 0; i < 16; ++i) acc[i] *= inv;
        }
        uint4 o0, o1;
        o0.x = (u32)f2bf(acc[0])  | ((u32)f2bf(acc[1])  << 16);
        o0.y = (u32)f2bf(acc[2])  | ((u32)f2bf(acc[3])  << 16);
        o0.z = (u32)f2bf(acc[4])  | ((u32)f2bf(acc[5])  << 16);
        o0.w = (u32)f2bf(acc[6])  | ((u32)f2bf(acc[7])  << 16);
        o1.x = (u32)f2bf(acc[8])  | ((u32)f2bf(acc[9])  << 16);
        o1.y = (u32)f2bf(acc[10]) | ((u32)f2bf(acc[11]) << 16);
        o1.z = (u32)f2bf(acc[12]) | ((u32)f2bf(acc[13]) << 16);
        o1.w = (u32)f2bf(acc[14]) | ((u32)f2bf(acc[15]) << 16);
        *(uint4*)&As[slot][c] = o0;
        *(uint4*)&As[slot][c + 8] = o1;
    }
    __syncthreads();

    // ---- phase 2: MFMA (4 waves; (stripe,half) covers 16 rows x 64 cols) ----
    int wave = t >> 6;                   // 0..3
    int lane = t & 63;
    int l15 = lane & 15;
    int q = lane >> 4;
    int stripe = wave >> 1;              // 0..1 -> 16-row stripe
    int half = wave & 1;                 // 0..1 -> col-blocks half*4 .. half*4+3
    int row_base = node0 + stripe * 16;

    f32x4 acc[4];
    #pragma unroll
    for (int i = 0; i < 4; ++i) acc[i] = (f32x4){0.f, 0.f, 0.f, 0.f};

    // p=0: A = agg tile (LDS), Wl (k<128)
    {
        const unsigned short* Wb = Wcat + (size_t)(half * 64 + l15) * 256 + q * 8;
        #pragma unroll
        for (int k0 = 0; k0 < 128; k0 += 32) {
            short8 a = *(const short8*)&As[stripe * 16 + l15][q * 8 + k0];
            #pragma unroll
            for (int j = 0; j < 4; ++j) {
                short8 b = *(const short8*)(Wb + (size_t)j * 16 * 256 + k0);
                acc[j] = __builtin_amdgcn_mfma_f32_16x16x32_bf16(a, b, acc[j], 0, 0, 0);
            }
        }
    }
    // p=1: A = h (global bf16, NONTEMPORAL: streamed once), Wr (k>=128)
    {
        const unsigned short* Ab = h + (size_t)(row_base + l15) * FDIM + q * 8;
        const unsigned short* Wb = Wcat + (size_t)(half * 64 + l15) * 256 + 128 + q * 8;
        #pragma unroll
        for (int k0 = 0; k0 < 128; k0 += 32) {
            short8 a = __builtin_nontemporal_load((const short8*)(Ab + k0));
            #pragma unroll
            for (int j = 0; j < 4; ++j) {
                short8 b = *(const short8*)(Wb + (size_t)j * 16 * 256 + k0);
                acc[j] = __builtin_amdgcn_mfma_f32_16x16x32_bf16(a, b, acc[j], 0, 0, 0);
            }
        }
    }

    if (pool_batch == nullptr) {
        // epilogue: bias + relu + nt bf16 store + fp4 pack (shfl pair -> byte) nt store
        #pragma unroll
        for (int j = 0; j < 4; ++j) {
            int col = (half * 4 + j) * 16 + l15;
            float bv = bias[col];
            #pragma unroll
            for (int r = 0; r < 4; ++r) {
                int row = row_base + q * 4 + r;
                float v = fmaxf(acc[j][r] + bv, 0.f);
                __builtin_nontemporal_store(f2bf(v), &out[(size_t)row * FDIM + col]);
                u32 code = f2fp4(v);
                u32 pc = (u32)__shfl_xor((int)code, 1);
                if ((l15 & 1) == 0)
                    __builtin_nontemporal_store((unsigned char)(code | (pc << 4)),
                                                &out4[(size_t)row * 64 + (col >> 1)]);
            }
        }
    } else {
        // layer-5 epilogue: stage relu tile in LDS, in-block sorted-batch reduction
        __syncthreads();                 // all waves done READING As (p=0)
        #pragma unroll
        for (int j = 0; j < 4; ++j) {
            int col = (half * 4 + j) * 16 + l15;
            float bv = bias[col];
            #pragma unroll
            for (int r = 0; r < 4; ++r) {
                int rl = stripe * 16 + q * 4 + r;
                As[rl][col] = f2bf(fmaxf(acc[j][r] + bv, 0.f));
            }
        }
        __syncthreads();
        if (t < FDIM) {
            int f = t;
            int nmax = min(32, N_NODES - node0);
            float a = 0.0f;
            int cur = pool_batch[node0];
            for (int r = 0; r < nmax; ++r) {
                int b = pool_batch[node0 + r];     // broadcast read
                if (b != cur) {
                    atomicAdd(&gsum[cur * FDIM + f], a);
                    a = 0.0f;
                    cur = b;
                }
                a += bflo((u32)As[r][f]);
            }
            atomicAdd(&gsum[cur * FDIM + f], a);
        }
    }
}

// ---------------- final MLP head (fp32): sigmoid(relu((gsum/cnt)@Wf1+bf1)@Wf2+bf2) -------
__global__ void mlp_kernel(const float* __restrict__ gsum,
                           const float* __restrict__ invcnt,
                           const float* __restrict__ Wf1, const float* __restrict__ bf1,
                           const float* __restrict__ Wf2, const float* __restrict__ bf2,
                           float* __restrict__ out) {
    int gg = blockIdx.x;
    int j = threadIdx.x;   // 128
    __shared__ float row[128];
    __shared__ float red[128];
    row[j] = gsum[gg * 128 + j] * invcnt[gg];
    __syncthreads();
    float acc = bf1[j];
    for (int k = 0; k < 128; ++k) acc = fmaf(row[k], Wf1[k * 128 + j], acc);
    float v = fmaxf(acc, 0.0f);
    red[j] = v * Wf2[j];
    __syncthreads();
    for (int off = 64; off > 0; off >>= 1) {
        if (j < off) red[j] += red[j + off];
        __syncthreads();
    }
    if (j == 0) out[gg] = 1.0f / (1.0f + expf(-(red[0] + bf2[0])));
}

extern "C" void kernel_launch(void* const* d_in, const int* in_sizes, int n_in,
                              void* d_out, int out_size, void* d_ws, size_t ws_size,
                              hipStream_t stream) {
    const float* x      = (const float*)d_in[0];
    const int*   edges  = (const int*)d_in[1];
    const int*   batch  = (const int*)d_in[2];
    WPtrs wp;
    const float* bs[5];
    for (int l = 0; l < 5; ++l) {
        wp.wl[l] = (const float*)d_in[3 + 3 * l];
        wp.wr[l] = (const float*)d_in[4 + 3 * l];
        bs[l]    = (const float*)d_in[5 + 3 * l];
    }
    const float* Wf1 = (const float*)d_in[18];
    const float* bf1 = (const float*)d_in[19];
    const float* Wf2 = (const float*)d_in[20];
    const float* bf2 = (const float*)d_in[21];
    float* out = (float*)d_out;

    // workspace carve-up (256B aligned)
    char* ws = (char*)d_ws;
    auto alloc = [&](size_t bytes) { void* p = (void*)ws; ws += (bytes + 255) & ~(size_t)255; return p; };
    unsigned short* xb   = (unsigned short*)alloc((size_t)MPAD * FDIM * 2);
    unsigned short* hA   = (unsigned short*)alloc((size_t)MPAD * FDIM * 2);
    unsigned short* hB   = (unsigned short*)alloc((size_t)MPAD * FDIM * 2);
    unsigned short* wcat = (unsigned short*)alloc((size_t)5 * 128 * 256 * 2);
    u32*   coarse   = (u32*)alloc((size_t)N_EDGES * 4);
    int*   g_hist   = (int*)alloc((size_t)NCB * ABLK * 4);
    int*   g_base   = (int*)alloc((size_t)NCB * ABLK * 4);
    int*   cbbase   = (int*)alloc((size_t)NCB * 4);
    int*   cbtotal  = (int*)alloc((size_t)NCB * 4);
    int*   row_ptr  = (int*)alloc((size_t)(N_NODES + 1) * 4);
    int*   csr_src  = (int*)alloc((size_t)N_EDGES * 4);
    float* invdeg   = (float*)alloc((size_t)N_NODES * 4);
    float* gsum     = (float*)alloc((size_t)NGRAPH * FDIM * 4);
    float* invcnt   = (float*)alloc((size_t)NGRAPH * 4);
    unsigned char* h4A = (unsigned char*)alloc((size_t)MPAD * 64);  // fp4 buffer (3.2 MB)
    // lifetime-aliased fp4 buffers (no extra ws):
    //   xb4 lives in hB  : read by layer 0 only; hB first written by layer 1.
    //   h4B lives in xb  : xb dead after layer 0; h4B written by layer 1.
    unsigned char* xb4 = (unsigned char*)hB;
    unsigned char* h4B = (unsigned char*)xb;
    (void)ws_size; (void)in_sizes; (void)n_in; (void)out_size;

    // ---- conversions + CSR build (deterministic multi-split, (dst,src-chunk) order) ----
    pre_kernel<<<CVT_BLOCKS + ABLK + WCONV_BLOCKS, 256, 0, stream>>>(
        x, xb, xb4, edges, g_hist, wp, wcat, batch, gsum, invcnt);
    scan1_kernel<<<NCB, 64, 0, stream>>>(g_hist, g_base, cbtotal);
    scan2_kernel<<<1, 256, 0, stream>>>(cbtotal, cbbase, row_ptr);
    scatter_kernel<<<ABLK, 256, 0, stream>>>(edges, g_base, cbbase, coarse);
    csr_kernel<<<NCB, 256, 0, stream>>>(cbbase, cbtotal, coarse, csr_src, row_ptr, invdeg);

    // ---- 5 fused SAGE layers; layer 5 folds the graph mean-pool ----
    const unsigned short* hcur  = xb;
    const unsigned char*  h4cur = xb4;
    unsigned short* bufs[2]  = {hA, hB};
    unsigned char*  bufs4[2] = {h4A, h4B};
    for (int l = 0; l < 5; ++l) {
        unsigned short* hnext  = bufs[l & 1];
        unsigned char*  h4next = (l == 4) ? nullptr : bufs4[l & 1];
        const int* pb = (l == 4) ? batch : nullptr;
        sage_fused_kernel<<<MPAD / 32, 256, 0, stream>>>(
            hcur, h4cur, row_ptr, csr_src, invdeg, wcat + ((size_t)l << 15), bs[l],
            hnext, h4next, pb, gsum);
        hcur = hnext;
        h4cur = bufs4[l & 1];
    }

    // ---- head ----
    mlp_kernel<<<NGRAPH, 128, 0, stream>>>(gsum, invcnt, Wf1, bf1, Wf2, bf2, out);
}